// Round 7
// baseline (603.694 us; speedup 1.0000x reference)
//
#include <hip/hip_runtime.h>
#include <stdint.h>

#define HD 2048
#define FD 1024
#define NE 16
#define NPAIR 8192
#define BM 128
#define MAXT 80

typedef short bf16x8 __attribute__((ext_vector_type(8)));
typedef float f32x4 __attribute__((ext_vector_type(4)));
typedef unsigned short u16;

static __device__ __forceinline__ u16 f2bf(float f) {
  uint32_t u = __float_as_uint(f);
  u += 0x7FFFu + ((u >> 16) & 1u);
  return (u16)(u >> 16);
}

// async global->LDS, 16B per lane, dest = wave-uniform base + lane*16
static __device__ __forceinline__ void async_copy16(const void* g, void* l) {
  __builtin_amdgcn_global_load_lds(
      (const __attribute__((address_space(1))) void*)g,
      (__attribute__((address_space(3))) void*)l, 16, 0, 0);
}

// Scale-folded byte tables for e2m1 -> bf16 dequant via v_perm.
struct DqTab { uint32_t hA, hB, lA, lB; };

static __device__ __forceinline__ DqTab make_tab(uint32_t sbits) {
  int n = (int)(sbits >> 23) - 127;
  int q = n >> 1;
  uint32_t r = (uint32_t)(n & 1);
  uint32_t mq = (uint32_t)(-q);
  uint32_t sub1 = mq * 0x01010100u;  // entry 0 (zero) untouched
  uint32_t subA = mq * 0x01010101u;
  DqTab t;
  t.hA = (r ? 0x40403F00u : 0x3F3F3F00u) - sub1;
  t.hB = (r ? 0x41414040u : 0x40404040u) - subA;
  t.lA = r ? 0x40008000u : 0xC0800000u;
  t.lB = r ? 0x4000C080u : 0xC0804000u;
  return t;
}

static __device__ __forceinline__ void dq8(uint32_t p, const DqTab& t, uint32_t* d) {
  uint32_t a = p & 0x0F0F0F0Fu;
  uint32_t b = (p >> 4) & 0x0F0F0F0Fu;
  uint32_t x0 = __builtin_amdgcn_perm(b, a, 0x05010400u);
  uint32_t x1 = __builtin_amdgcn_perm(b, a, 0x07030602u);
  uint32_t m0 = x0 & 0x07070707u;
  uint32_t m1 = x1 & 0x07070707u;
  uint32_t h0 = __builtin_amdgcn_perm(t.hB, t.hA, m0) | ((x0 & 0x08080808u) << 4);
  uint32_t h1 = __builtin_amdgcn_perm(t.hB, t.hA, m1) | ((x1 & 0x08080808u) << 4);
  uint32_t l0 = __builtin_amdgcn_perm(t.lB, t.lA, m0);
  uint32_t l1 = __builtin_amdgcn_perm(t.lB, t.lA, m1);
  d[0] = __builtin_amdgcn_perm(h0, l0, 0x05010400u);
  d[1] = __builtin_amdgcn_perm(h0, l0, 0x07030602u);
  d[2] = __builtin_amdgcn_perm(h1, l1, 0x05010400u);
  d[3] = __builtin_amdgcn_perm(h1, l1, 0x07030602u);
}

static __device__ __forceinline__ uint32_t pack4(int4 v) {
  return (uint32_t)(v.x & 0xFF) | ((uint32_t)(v.y & 0xFF) << 8) |
         ((uint32_t)(v.z & 0xFF) << 16) | ((uint32_t)v.w << 24);
}

__global__ void cast_kernel(const float* __restrict__ x, u16* __restrict__ xb) {
  int i = blockIdx.x * 256 + threadIdx.x;
  float4 v = ((const float4*)x)[i];
  ushort4 o;
  o.x = f2bf(v.x); o.y = f2bf(v.y); o.z = f2bf(v.z); o.w = f2bf(v.w);
  ((ushort4*)xb)[i] = o;
}

__global__ void zero_kernel(float4* __restrict__ out) {
  out[blockIdx.x * 256 + threadIdx.x] = float4{0.f, 0.f, 0.f, 0.f};
}

__global__ void route_kernel(const int* __restrict__ ids, const float* __restrict__ tw,
                             int* __restrict__ rows, float* __restrict__ rw,
                             int* __restrict__ te) {
  __shared__ int cnt[NE], base[NE], run[NE];
  int tid = threadIdx.x;
  if (tid < NE) { cnt[tid] = 0; run[tid] = 0; }
  __syncthreads();
  for (int i = tid; i < NPAIR; i += 256) atomicAdd(&cnt[ids[i]], 1);
  __syncthreads();
  if (tid == 0) {
    int cum = 0;
    for (int e = 0; e < NE; ++e) {
      base[e] = cum;
      int nt = (cnt[e] + BM - 1) >> 7;
      for (int j = 0; j < nt; ++j) te[(cum >> 7) + j] = e;
      cum += nt << 7;
    }
    for (int t = cum >> 7; t < MAXT; ++t) te[t] = -1;
  }
  __syncthreads();
  for (int i = tid; i < MAXT * BM; i += 256) { rows[i] = -1; rw[i] = 0.f; }
  __syncthreads();
  for (int i = tid; i < NPAIR; i += 256) {
    int e = ids[i];
    int p = base[e] + atomicAdd(&run[e], 1);
    rows[p] = i >> 2;
    rw[p] = tw[i];
  }
}

// gate_up GEMM + SwiGLU + rw -> act. BM=128, BN=64g+64u, BK=32.
// m97-style: 2 barriers; A via global_load_lds (double-buffered), B via
// register-prefetch + v_perm dequant. All global issues AFTER barrier 2.
__global__ __launch_bounds__(256, 2) void gemm1_kernel(
    const u16* __restrict__ xb, const int* __restrict__ gup32,
    const uint32_t* __restrict__ gus, const int* __restrict__ rows,
    const float* __restrict__ rw, const int* __restrict__ te,
    u16* __restrict__ act) {
  const int tile = blockIdx.y;
  const int e = te[tile];
  if (e < 0) return;
  const int f0 = blockIdx.x * 64;

  __shared__ u16 sA[2][4096];   // [buf][chunk4][row128][8el]
  __shared__ u16 sB[4096];      // [chunk4][row128][8el]; rows 0-63 gate, 64-127 up
  __shared__ int rows_s[BM];
  __shared__ float rw_s[BM];

  const int tid = threadIdx.x;
  if (tid < BM) {
    rows_s[tid] = rows[tile * BM + tid];
    rw_s[tid] = rw[tile * BM + tid];
  }
  __syncthreads();

  const int l = tid & 63;
  const int w = tid >> 6;
  // A: wave w stages k-chunk w (8 els, 16B) for rows h*64+l
  int r0 = rows_s[l]; r0 = r0 < 0 ? 0 : r0;
  int r1 = rows_s[64 + l]; r1 = r1 < 0 ? 0 : r1;
  const u16* pa0 = xb + (size_t)r0 * HD + w * 8;
  const u16* pa1 = xb + (size_t)r1 * HD + w * 8;

  // B staging: thread -> row rB, half skh (16 els = chunks 2*skh, 2*skh+1)
  const int rB = tid >> 1;
  const int skh = tid & 1;
  const int o = (rB < 64) ? (f0 + rB) : (960 + f0 + rB);
  const int* bptr = gup32 + (size_t)(e * 2048 + o) * 1024 + skh * 8;
  const uint32_t* sptr = gus + (size_t)(e * 2048 + o) * 64;
  u16* wb0 = &sB[(2 * skh) * 1024 + rB * 8];
  u16* wb1 = &sB[(2 * skh + 1) * 1024 + rB * 8];

  const int wm = w >> 1, wn = w & 1;
  const int q = l >> 4, c = l & 15;

  f32x4 Cg[4][2], Cu[4][2];
#pragma unroll
  for (int s = 0; s < 4; ++s)
#pragma unroll
    for (int t2 = 0; t2 < 2; ++t2) {
      Cg[s][t2] = f32x4{0.f, 0.f, 0.f, 0.f};
      Cu[s][t2] = f32x4{0.f, 0.f, 0.f, 0.f};
    }

  // prologue: A(0) async into sA[0]; B(0) into regs
  async_copy16(pa0, &sA[0][(2 * w) * 512]);
  async_copy16(pa1, &sA[0][(2 * w) * 512 + 512]);
  int4 nw0 = *(const int4*)(bptr);
  int4 nw1 = *(const int4*)(bptr + 4);
  uint32_t nsb = sptr[0];

  for (int kk = 0; kk < 64; ++kk) {
    const int p = kk & 1;
    __syncthreads();                       // b1: drains A(kk) dma + B(kk) regs
    {
      DqTab t = make_tab(nsb);
      uint32_t d0[4], d1[4];
      dq8(pack4(nw0), t, d0);
      dq8(pack4(nw1), t, d1);
      *(uint4*)wb0 = make_uint4(d0[0], d0[1], d0[2], d0[3]);
      *(uint4*)wb1 = make_uint4(d1[0], d1[1], d1[2], d1[3]);
    }
    __syncthreads();                       // b2: staging visible
    if (kk < 63) {                         // issue kk+1 traffic; flies during MFMA
      const int ko = (kk + 1) * 32;
      async_copy16(pa0 + ko, &sA[p ^ 1][(2 * w) * 512]);
      async_copy16(pa1 + ko, &sA[p ^ 1][(2 * w) * 512 + 512]);
      nw0 = *(const int4*)(bptr + (kk + 1) * 16);
      nw1 = *(const int4*)(bptr + (kk + 1) * 16 + 4);
      nsb = sptr[kk + 1];
    }

    bf16x8 af[4], bg[2], bu[2];
#pragma unroll
    for (int s = 0; s < 4; ++s)
      af[s] = *(const bf16x8*)&sA[p][q * 1024 + (wm * 64 + s * 16 + c) * 8];
#pragma unroll
    for (int t2 = 0; t2 < 2; ++t2) {
      bg[t2] = *(const bf16x8*)&sB[q * 1024 + (wn * 32 + t2 * 16 + c) * 8];
      bu[t2] = *(const bf16x8*)&sB[q * 1024 + (64 + wn * 32 + t2 * 16 + c) * 8];
    }
#pragma unroll
    for (int s = 0; s < 4; ++s)
#pragma unroll
      for (int t2 = 0; t2 < 2; ++t2) {
        Cg[s][t2] = __builtin_amdgcn_mfma_f32_16x16x32_bf16(af[s], bg[t2], Cg[s][t2], 0, 0, 0);
        Cu[s][t2] = __builtin_amdgcn_mfma_f32_16x16x32_bf16(af[s], bu[t2], Cu[s][t2], 0, 0, 0);
      }
  }

#pragma unroll
  for (int s = 0; s < 4; ++s) {
    const int mlb = wm * 64 + s * 16 + q * 4;
#pragma unroll
    for (int t2 = 0; t2 < 2; ++t2) {
      const int fg = f0 + wn * 32 + t2 * 16 + c;
#pragma unroll
      for (int r = 0; r < 4; ++r) {
        const int ml = mlb + r;
        float g = Cg[s][t2][r];
        float u = Cu[s][t2][r];
        float aval = g / (1.f + __expf(-g)) * u * rw_s[ml];
        act[(size_t)(tile * BM + ml) * FD + fg] = f2bf(aval);
      }
    }
  }
}

// down GEMM -> atomic out. BM=128, BN=128, BK=32. Same structure.
__global__ __launch_bounds__(256, 2) void gemm2_kernel(
    const u16* __restrict__ act, const int* __restrict__ dwn32,
    const uint32_t* __restrict__ dsc, const int* __restrict__ rows,
    const int* __restrict__ te, float* __restrict__ out) {
  const int tile = blockIdx.y;
  const int e = te[tile];
  if (e < 0) return;
  const int h0 = blockIdx.x * 128;

  __shared__ u16 sA[2][4096];
  __shared__ u16 sB[4096];      // [chunk4][row128][8el]; rows = h-cols h0..h0+127
  __shared__ int rows_s[BM];

  const int tid = threadIdx.x;
  if (tid < BM) rows_s[tid] = rows[tile * BM + tid];
  __syncthreads();

  const int l = tid & 63;
  const int w = tid >> 6;
  const u16* pa0 = act + (size_t)(tile * BM + l) * FD + w * 8;
  const u16* pa1 = act + (size_t)(tile * BM + 64 + l) * FD + w * 8;

  const int rB = tid >> 1;
  const int skh = tid & 1;
  const int o = h0 + rB;
  const int* bptr = dwn32 + (size_t)(e * 2048 + o) * 512 + skh * 8;
  const uint32_t* sptr = dsc + (size_t)(e * 2048 + o) * 32;
  u16* wb0 = &sB[(2 * skh) * 1024 + rB * 8];
  u16* wb1 = &sB[(2 * skh + 1) * 1024 + rB * 8];

  const int wm = w >> 1, wn = w & 1;
  const int q = l >> 4, c = l & 15;

  f32x4 Cd[4][4];
#pragma unroll
  for (int s = 0; s < 4; ++s)
#pragma unroll
    for (int t2 = 0; t2 < 4; ++t2) Cd[s][t2] = f32x4{0.f, 0.f, 0.f, 0.f};

  async_copy16(pa0, &sA[0][(2 * w) * 512]);
  async_copy16(pa1, &sA[0][(2 * w) * 512 + 512]);
  int4 nw0 = *(const int4*)(bptr);
  int4 nw1 = *(const int4*)(bptr + 4);
  uint32_t nsb = sptr[0];

  for (int kk = 0; kk < 32; ++kk) {
    const int p = kk & 1;
    __syncthreads();
    {
      DqTab t = make_tab(nsb);
      uint32_t d0[4], d1[4];
      dq8(pack4(nw0), t, d0);
      dq8(pack4(nw1), t, d1);
      *(uint4*)wb0 = make_uint4(d0[0], d0[1], d0[2], d0[3]);
      *(uint4*)wb1 = make_uint4(d1[0], d1[1], d1[2], d1[3]);
    }
    __syncthreads();
    if (kk < 31) {
      const int ko = (kk + 1) * 32;
      async_copy16(pa0 + ko, &sA[p ^ 1][(2 * w) * 512]);
      async_copy16(pa1 + ko, &sA[p ^ 1][(2 * w) * 512 + 512]);
      nw0 = *(const int4*)(bptr + (kk + 1) * 16);
      nw1 = *(const int4*)(bptr + (kk + 1) * 16 + 4);
      nsb = sptr[kk + 1];
    }

    bf16x8 af[4], bf_[4];
#pragma unroll
    for (int s = 0; s < 4; ++s)
      af[s] = *(const bf16x8*)&sA[p][q * 1024 + (wm * 64 + s * 16 + c) * 8];
#pragma unroll
    for (int t2 = 0; t2 < 4; ++t2)
      bf_[t2] = *(const bf16x8*)&sB[q * 1024 + (wn * 64 + t2 * 16 + c) * 8];
#pragma unroll
    for (int s = 0; s < 4; ++s)
#pragma unroll
      for (int t2 = 0; t2 < 4; ++t2)
        Cd[s][t2] = __builtin_amdgcn_mfma_f32_16x16x32_bf16(af[s], bf_[t2], Cd[s][t2], 0, 0, 0);
  }

#pragma unroll
  for (int s = 0; s < 4; ++s) {
    const int mlb = wm * 64 + s * 16 + q * 4;
#pragma unroll
    for (int t2 = 0; t2 < 4; ++t2) {
      const int hg = h0 + wn * 64 + t2 * 16 + c;
#pragma unroll
      for (int r = 0; r < 4; ++r) {
        int token = rows_s[mlb + r];
        if (token >= 0) atomicAdd(&out[(size_t)token * HD + hg], Cd[s][t2][r]);
      }
    }
  }
}

extern "C" void kernel_launch(void* const* d_in, const int* in_sizes, int n_in,
                              void* d_out, int out_size, void* d_ws, size_t ws_size,
                              hipStream_t stream) {
  const float* hidden = (const float*)d_in[0];
  const float* tw = (const float*)d_in[1];
  const int* ids = (const int*)d_in[2];
  const int* gup32 = (const int*)d_in[3];        // uint8 packed bytes, uploaded as int32
  const uint32_t* gus = (const uint32_t*)d_in[4];
  const int* dwn32 = (const int*)d_in[5];
  const uint32_t* dsc = (const uint32_t*)d_in[6];
  float* out = (float*)d_out;

  char* ws = (char*)d_ws;
  int* rows = (int*)(ws);                    // 40 KB
  float* rw = (float*)(ws + 49152);          // 40 KB
  int* te = (int*)(ws + 98304);              // 320 B
  u16* xb = (u16*)(ws + 131072);             // 8 MB
  u16* act = (u16*)(ws + 8519680);           // 20 MB -> total ~28.9 MB (known-safe)

  cast_kernel<<<dim3(4096), dim3(256), 0, stream>>>(hidden, xb);
  zero_kernel<<<dim3(4096), dim3(256), 0, stream>>>((float4*)out);
  route_kernel<<<dim3(1), dim3(256), 0, stream>>>(ids, tw, rows, rw, te);
  gemm1_kernel<<<dim3(16, MAXT), dim3(256), 0, stream>>>(xb, gup32, gus, rows, rw, te, act);
  gemm2_kernel<<<dim3(16, MAXT), dim3(256), 0, stream>>>(act, dwn32, dsc, rows, te, out);
}